// Round 6
// baseline (275.571 us; speedup 1.0000x reference)
//
#include <hip/hip_runtime.h>

#define DN 384
#define DS 512
#define DMSA 64
#define DH 32
#define DP 128

typedef __bf16 bf16x8 __attribute__((ext_vector_type(8)));
typedef __bf16 bf16x4 __attribute__((ext_vector_type(4)));
typedef float f32x4 __attribute__((ext_vector_type(4)));
typedef float f32x16 __attribute__((ext_vector_type(16)));

// ws layout (bytes)
#define OFF_BT  12582912u
#define OFF_WT  25165824u   // wt bf16 [kk 64][p 128][ks 16] = 256KB
#define OFF_INV 25427968u
#define OFF_SMF 25428224u
#define OFF_MKF 25430272u

__device__ __forceinline__ void async16(const void* g, void* l) {
  __builtin_amdgcn_global_load_lds((const __attribute__((address_space(1))) unsigned*)g,
                                   (__attribute__((address_space(3))) unsigned*)l, 16, 0, 0);
}

// ---------------------------------------------------------------------------
// prep: masks, 1/num_msa, w_out -> wt [kk][p][ks] (k'=e*32+d).
// ---------------------------------------------------------------------------
__global__ __launch_bounds__(128) void prep_kernel(const void* __restrict__ mask_raw,
                                                   const void* __restrict__ msa_mask_raw,
                                                   const float* __restrict__ w_out,
                                                   __bf16* __restrict__ wt,
                                                   float* __restrict__ invp,
                                                   float* __restrict__ smf,
                                                   float* __restrict__ mkf) {
  const int blk = blockIdx.x;
  const int tid = threadIdx.x;
  if (blk == 0) {
    __shared__ int sh[128];
    const unsigned int* u = (const unsigned int*)msa_mask_raw;
    int bad = (u[tid] > 1u) ? 1 : 0;
    sh[tid] = bad;
    __syncthreads();
    for (int off = 64; off > 0; off >>= 1) {
      if (tid < off) sh[tid] |= sh[tid + off];
      __syncthreads();
    }
    const int int_mode = (sh[0] == 0);
    __syncthreads();
    int cnt = 0;
    for (int q = tid; q < DS; q += 128) {
      float v;
      if (int_mode) v = (((const int*)msa_mask_raw)[q] != 0) ? 1.f : 0.f;
      else          v = (((const unsigned char*)msa_mask_raw)[q] != 0) ? 1.f : 0.f;
      smf[q] = v;
      cnt += (v != 0.f) ? 1 : 0;
    }
    sh[tid] = cnt;
    __syncthreads();
    for (int off = 64; off > 0; off >>= 1) {
      if (tid < off) sh[tid] += sh[tid + off];
      __syncthreads();
    }
    if (tid == 0) {
      float num = (float)sh[0];
      if (num < 1e-5f) num = 1e-5f;
      invp[0] = 1.0f / num;
    }
  } else if (blk == 1) {
    __shared__ int sh[128];
    const unsigned int* u = (const unsigned int*)mask_raw;
    int bad = 0;
    if (tid < 96) bad = (u[tid] > 1u) ? 1 : 0;
    sh[tid] = bad;
    __syncthreads();
    for (int off = 64; off > 0; off >>= 1) {
      if (tid < off) sh[tid] |= sh[tid + off];
      __syncthreads();
    }
    const int int_mode = (sh[0] == 0);
    __syncthreads();
    for (int q = tid; q < DN; q += 128) {
      float v;
      if (int_mode) v = (((const int*)mask_raw)[q] != 0) ? 1.f : 0.f;
      else          v = (((const unsigned char*)mask_raw)[q] != 0) ? 1.f : 0.f;
      mkf[q] = v;
    }
  } else {
    const int kw = blk - 2;                      // k = d*32+e
    const int p = tid;                           // 0..127
    const int kp = (kw & 31) * 32 + (kw >> 5);   // k' = e*32+d
    const int kk = kp >> 4, ks = kp & 15;
    wt[((size_t)kk * 128 + p) * 16 + ks] = (__bf16)w_out[(size_t)kw * DP + p];
  }
}

// ---------------------------------------------------------------------------
// ln_proj: LN(64) -> x@w_hidden (LDS-broadcast weights) -> mask/scale ->
// at/bt [n*32+c][s] bf16.
// ---------------------------------------------------------------------------
__global__ __launch_bounds__(256) void ln_proj_kernel(const float* __restrict__ msa,
                                                      const float* __restrict__ gamma,
                                                      const float* __restrict__ beta,
                                                      const float* __restrict__ w_hidden,
                                                      const float* __restrict__ invp,
                                                      const float* __restrict__ smf,
                                                      __bf16* __restrict__ at,
                                                      __bf16* __restrict__ bt) {
  __shared__ float wl[DMSA * 2 * DH];
  __shared__ float gl[DMSA], bl[DMSA];
  const int tid = threadIdx.x;
  for (int q = tid; q < DMSA * 2 * DH; q += 256) wl[q] = w_hidden[q];
  if (tid < DMSA) { gl[tid] = gamma[tid]; bl[tid] = beta[tid]; }
  __syncthreads();

  const int p = blockIdx.x * 256 + tid;
  const int n = p >> 9;
  const int s = p & 511;

  const float* mp = msa + ((size_t)s * DN + n) * DMSA;
  float x[64];
  float sum = 0.f, sq = 0.f;
#pragma unroll
  for (int q = 0; q < 16; ++q) {
    float4 v = ((const float4*)mp)[q];
    x[4 * q + 0] = v.x; x[4 * q + 1] = v.y; x[4 * q + 2] = v.z; x[4 * q + 3] = v.w;
    sum += v.x + v.y + v.z + v.w;
    sq  += v.x * v.x + v.y * v.y + v.z * v.z + v.w * v.w;
  }
  const float mu = sum * (1.f / 64.f);
  const float var = sq * (1.f / 64.f) - mu * mu;
  const float rstd = rsqrtf(var + 1e-5f);
#pragma unroll
  for (int d = 0; d < 64; ++d) x[d] = (x[d] - mu) * rstd * gl[d] + bl[d];

  const float sm = smf[s];
  const float sa = sm * invp[0];

  const size_t outbase = ((size_t)n * DH) * DS + s;
  for (int c = 0; c < DH; ++c) {
    float ha = 0.f, hb = 0.f;
#pragma unroll
    for (int d = 0; d < 64; ++d) {
      ha += x[d] * wl[d * 64 + c];
      hb += x[d] * wl[d * 64 + DH + c];
    }
    at[outbase + (size_t)c * DS] = (__bf16)(ha * sa);
    bt[outbase + (size_t)c * DS] = (__bf16)(hb * sm);
  }
}

// ---------------------------------------------------------------------------
// fused: GEMM1 256x256xK512, 16 halves (BK=32) on a 4-slot ring, each half =
// 2 fine phases {ds_read, stage, barrier, lgkm0, setprio+16 MFMA, barrier}
// with counted vmcnt at half boundaries (T3+T4+T5 per m201). Then op->LDS
// (swizzled) -> GEMM2 via 32x32x16 MFMA (wt [kk][p][16], rolling prefetch).
// ---------------------------------------------------------------------------
__global__ __launch_bounds__(512, 2) void fused_kernel(const __bf16* __restrict__ at,
                                                       const __bf16* __restrict__ bt,
                                                       const __bf16* __restrict__ wt,
                                                       const float* __restrict__ mkf,
                                                       const float* __restrict__ b_out,
                                                       float* __restrict__ out) {
  // ring: 4 slots x (A 16KB + B 16KB) = 128KB; aliased: opl 64x2064B = 129KB
  __shared__ __align__(128) char smem[132096];

  const int tid = threadIdx.x;
  const int l = tid & 63, w = tid >> 6;
  const int lr = l & 15, lk = l >> 4;
  const int wr = w >> 2, wc = w & 3;

  // XCD-aware swizzle: 48 supertiles of 8x6 blocks.
  const int orig = blockIdx.x;
  const int xcd = orig & 7, sidx = orig >> 3;
  const int stl = sidx / 48, u = sidx % 48;
  const int stg = xcd + stl * 8;
  const int stx = stg % 6, sty = stg / 6;
  const int bx = stx * 8 + (u & 7);
  const int by = sty * 6 + (u >> 3);

  // staging lane geometry (BK=32 half: row=64B=4 chunks, chunk ^= row&3)
  const int rowL = w * 32 + (l >> 2);
  const int chunkL = (l & 3) ^ ((l >> 2) & 3);
  const __bf16* gAb = at + (size_t)(bx * 256 + rowL) * 512 + chunkL * 8;
  const __bf16* gBb = bt + (size_t)(by * 256 + rowL) * 512 + chunkL * 8;

  f32x4 acc[8][4];
#pragma unroll
  for (int i = 0; i < 8; ++i)
#pragma unroll
    for (int j = 0; j < 4; ++j) acc[i][j] = (f32x4){0.f, 0.f, 0.f, 0.f};

  // stage part p (0/1: 16 rows of A + 16 rows of B) of half h into slot h&3
  auto STAGE2 = [&](int h, int p) {
    char* da = smem + (h & 3) * 32768 + w * 2048 + p * 1024;
    char* db = da + 16384;
    const int go = h * 32 + p * 16 * 512;
    async16(gAb + go, da);
    async16(gBb + go, db);
  };

#pragma unroll
  for (int h = 0; h < 3; ++h) {
    STAGE2(h, 0);
    STAGE2(h, 1);
  }
  asm volatile("s_waitcnt vmcnt(8)" ::: "memory");
  __builtin_amdgcn_s_barrier();

#pragma unroll
  for (int h = 0; h < 16; ++h) {
    const char* A = smem + (h & 3) * 32768;
    const char* B = A + 16384;
    bf16x8 af[4], bfr[4];

    // ---- phase 0: read B0..3 + A0..3, stage part0, MFMA quad 0 ----
#pragma unroll
    for (int fj = 0; fj < 4; ++fj) {
      const int r = wc * 64 + fj * 16 + lr;
      bfr[fj] = *(const bf16x8*)(B + r * 64 + (lk ^ (lr & 3)) * 16);
    }
#pragma unroll
    for (int fi = 0; fi < 4; ++fi) {
      const int r = wr * 128 + fi * 16 + lr;
      af[fi] = *(const bf16x8*)(A + r * 64 + (lk ^ (lr & 3)) * 16);
    }
    if (h < 13) STAGE2(h + 3, 0);
    __builtin_amdgcn_s_barrier();
    asm volatile("s_waitcnt lgkmcnt(0)" ::: "memory");
    __builtin_amdgcn_sched_barrier(0);
    __builtin_amdgcn_s_setprio(1);
#pragma unroll
    for (int fi = 0; fi < 4; ++fi)
#pragma unroll
      for (int fj = 0; fj < 4; ++fj)
        acc[fi][fj] = __builtin_amdgcn_mfma_f32_16x16x32_bf16(af[fi], bfr[fj], acc[fi][fj], 0, 0, 0);
    __builtin_amdgcn_s_setprio(0);
    __builtin_amdgcn_s_barrier();

    // ---- phase 1: read A4..7, stage part1, publish next slot, MFMA quad 1 ----
#pragma unroll
    for (int fi = 0; fi < 4; ++fi) {
      const int r = wr * 128 + (4 + fi) * 16 + lr;
      af[fi] = *(const bf16x8*)(A + r * 64 + (lk ^ (lr & 3)) * 16);
    }
    if (h < 13) STAGE2(h + 3, 1);
    if (h <= 12)      asm volatile("s_waitcnt vmcnt(8)" ::: "memory");
    else if (h == 13) asm volatile("s_waitcnt vmcnt(4)" ::: "memory");
    else if (h == 14) asm volatile("s_waitcnt vmcnt(0)" ::: "memory");
    __builtin_amdgcn_s_barrier();
    asm volatile("s_waitcnt lgkmcnt(0)" ::: "memory");
    __builtin_amdgcn_sched_barrier(0);
    __builtin_amdgcn_s_setprio(1);
#pragma unroll
    for (int fi = 0; fi < 4; ++fi)
#pragma unroll
      for (int fj = 0; fj < 4; ++fj)
        acc[4 + fi][fj] = __builtin_amdgcn_mfma_f32_16x16x32_bf16(af[fi], bfr[fj], acc[4 + fi][fj], 0, 0, 0);
    __builtin_amdgcn_s_setprio(0);
    __builtin_amdgcn_s_barrier();
  }

  // ---- op tile -> LDS bf16 as A2[pair][k'=e*32+d], chunk-XOR swizzled ----
#pragma unroll
  for (int fi = 0; fi < 8; ++fi) {
    const int i_l = wr * 4 + (fi >> 1);
#pragma unroll
    for (int fj = 0; fj < 4; ++fj) {
      const int col = wc * 64 + fj * 16 + lr;
      const int j_l = col >> 5, e = col & 31;
      const int pair = i_l * 8 + j_l;
      const int cw = e * 4 + (fi & 1) * 2 + (lk >> 1);
      const int phys = cw ^ (e & 7);
      bf16x4 pk;
      pk[0] = (__bf16)acc[fi][fj][0];
      pk[1] = (__bf16)acc[fi][fj][1];
      pk[2] = (__bf16)acc[fi][fj][2];
      pk[3] = (__bf16)acc[fi][fj][3];
      *(bf16x4*)(smem + pair * 2064 + phys * 16 + (lk & 1) * 8) = pk;
    }
  }

  // GEMM2 geometry + first B-frag prefetch (hides L2 latency under barrier)
  const int mf = w >> 2, pf = w & 3;
  const int l31 = l & 31, lh = l >> 5;
  const __bf16* wb = wt + (size_t)(pf * 32 + l31) * 16 + lh * 8;  // + kk*2048
  bf16x8 b2 = *(const bf16x8*)(wb);

  asm volatile("s_waitcnt lgkmcnt(0)" ::: "memory");
  __builtin_amdgcn_s_barrier();

  // ---- GEMM2: C2[64 pairs][128 p], K=1024, 32x32x16 MFMA, 1 frag/wave ----
  f32x16 acc2;
#pragma unroll
  for (int q = 0; q < 16; ++q) acc2[q] = 0.f;

  const char* aBase = smem + (mf * 32 + l31) * 2064;
#pragma unroll 4
  for (int kk = 0; kk < 64; ++kk) {
    bf16x8 b2n;
    if (kk < 63) b2n = *(const bf16x8*)(wb + (size_t)(kk + 1) * 2048);
    const int cw = kk * 2 + lh;
    const int phys = cw ^ ((kk >> 1) & 7);
    const bf16x8 a2 = *(const bf16x8*)(aBase + phys * 16);
    acc2 = __builtin_amdgcn_mfma_f32_32x32x16_bf16(a2, b2, acc2, 0, 0, 0);
    b2 = b2n;
  }

  const int p = pf * 32 + l31;
  const float bo = b_out[p];
#pragma unroll
  for (int reg = 0; reg < 16; ++reg) {
    const int pair = mf * 32 + (reg & 3) + 8 * (reg >> 2) + 4 * lh;
    const int i = bx * 8 + (pair >> 3);
    const int j = by * 8 + (pair & 7);
    const float pm = mkf[i] * mkf[j];
    out[((size_t)i * DN + j) * DP + p] = acc2[reg] * pm + bo;
  }
}

extern "C" void kernel_launch(void* const* d_in, const int* in_sizes, int n_in,
                              void* d_out, int out_size, void* d_ws, size_t ws_size,
                              hipStream_t stream) {
  const float* msa      = (const float*)d_in[0];
  const void*  mask     = d_in[1];
  const void*  msa_mask = d_in[2];
  const float* gamma    = (const float*)d_in[3];
  const float* beta     = (const float*)d_in[4];
  const float* w_hidden = (const float*)d_in[5];
  const float* w_out    = (const float*)d_in[6];
  const float* b_out    = (const float*)d_in[7];
  float* out = (float*)d_out;

  char* ws = (char*)d_ws;
  __bf16* at  = (__bf16*)ws;
  __bf16* bt  = (__bf16*)(ws + OFF_BT);
  __bf16* wt  = (__bf16*)(ws + OFF_WT);
  float*  inv = (float*)(ws + OFF_INV);
  float*  smf = (float*)(ws + OFF_SMF);
  float*  mkf = (float*)(ws + OFF_MKF);

  prep_kernel<<<1026, 128, 0, stream>>>(mask, msa_mask, w_out, wt, inv, smf, mkf);
  ln_proj_kernel<<<768, 256, 0, stream>>>(msa, gamma, beta, w_hidden, inv, smf, at, bt);
  fused_kernel<<<2304, 512, 0, stream>>>(at, bt, wt, mkf, b_out, out);
}

// Round 7
// 255.595 us; speedup vs baseline: 1.0782x; 1.0782x over previous
//
#include <hip/hip_runtime.h>

#define DN 384
#define DS 512
#define DMSA 64
#define DH 32
#define DP 128

typedef __bf16 bf16x8 __attribute__((ext_vector_type(8)));
typedef __bf16 bf16x4 __attribute__((ext_vector_type(4)));
typedef float f32x4 __attribute__((ext_vector_type(4)));
typedef float f32x16 __attribute__((ext_vector_type(16)));

// ws layout (bytes)
#define OFF_BT  12582912u
#define OFF_WT  25165824u   // wt bf16 [kk 64][p 128][ks 16] = 256KB
#define OFF_INV 25427968u
#define OFF_SMF 25428224u
#define OFF_MKF 25430272u

__device__ __forceinline__ void async16(const void* g, void* l) {
  __builtin_amdgcn_global_load_lds((const __attribute__((address_space(1))) unsigned*)g,
                                   (__attribute__((address_space(3))) unsigned*)l, 16, 0, 0);
}

// ---------------------------------------------------------------------------
// prep: masks, 1/num_msa, w_out -> wt [kk][p][ks] (k'=e*32+d).
// ---------------------------------------------------------------------------
__global__ __launch_bounds__(128) void prep_kernel(const void* __restrict__ mask_raw,
                                                   const void* __restrict__ msa_mask_raw,
                                                   const float* __restrict__ w_out,
                                                   __bf16* __restrict__ wt,
                                                   float* __restrict__ invp,
                                                   float* __restrict__ smf,
                                                   float* __restrict__ mkf) {
  const int blk = blockIdx.x;
  const int tid = threadIdx.x;
  if (blk == 0) {
    __shared__ int sh[128];
    const unsigned int* u = (const unsigned int*)msa_mask_raw;
    int bad = (u[tid] > 1u) ? 1 : 0;
    sh[tid] = bad;
    __syncthreads();
    for (int off = 64; off > 0; off >>= 1) {
      if (tid < off) sh[tid] |= sh[tid + off];
      __syncthreads();
    }
    const int int_mode = (sh[0] == 0);
    __syncthreads();
    int cnt = 0;
    for (int q = tid; q < DS; q += 128) {
      float v;
      if (int_mode) v = (((const int*)msa_mask_raw)[q] != 0) ? 1.f : 0.f;
      else          v = (((const unsigned char*)msa_mask_raw)[q] != 0) ? 1.f : 0.f;
      smf[q] = v;
      cnt += (v != 0.f) ? 1 : 0;
    }
    sh[tid] = cnt;
    __syncthreads();
    for (int off = 64; off > 0; off >>= 1) {
      if (tid < off) sh[tid] += sh[tid + off];
      __syncthreads();
    }
    if (tid == 0) {
      float num = (float)sh[0];
      if (num < 1e-5f) num = 1e-5f;
      invp[0] = 1.0f / num;
    }
  } else if (blk == 1) {
    __shared__ int sh[128];
    const unsigned int* u = (const unsigned int*)mask_raw;
    int bad = 0;
    if (tid < 96) bad = (u[tid] > 1u) ? 1 : 0;
    sh[tid] = bad;
    __syncthreads();
    for (int off = 64; off > 0; off >>= 1) {
      if (tid < off) sh[tid] |= sh[tid + off];
      __syncthreads();
    }
    const int int_mode = (sh[0] == 0);
    __syncthreads();
    for (int q = tid; q < DN; q += 128) {
      float v;
      if (int_mode) v = (((const int*)mask_raw)[q] != 0) ? 1.f : 0.f;
      else          v = (((const unsigned char*)mask_raw)[q] != 0) ? 1.f : 0.f;
      mkf[q] = v;
    }
  } else {
    const int kw = blk - 2;                      // k = d*32+e
    const int p = tid;                           // 0..127
    const int kp = (kw & 31) * 32 + (kw >> 5);   // k' = e*32+d
    const int kk = kp >> 4, ks = kp & 15;
    wt[((size_t)kk * 128 + p) * 16 + ks] = (__bf16)w_out[(size_t)kw * DP + p];
  }
}

// ---------------------------------------------------------------------------
// ln_proj: LN(64) -> x@w_hidden (LDS-broadcast weights) -> mask/scale ->
// at/bt [n*32+c][s] bf16.
// ---------------------------------------------------------------------------
__global__ __launch_bounds__(256) void ln_proj_kernel(const float* __restrict__ msa,
                                                      const float* __restrict__ gamma,
                                                      const float* __restrict__ beta,
                                                      const float* __restrict__ w_hidden,
                                                      const float* __restrict__ invp,
                                                      const float* __restrict__ smf,
                                                      __bf16* __restrict__ at,
                                                      __bf16* __restrict__ bt) {
  __shared__ float wl[DMSA * 2 * DH];
  __shared__ float gl[DMSA], bl[DMSA];
  const int tid = threadIdx.x;
  for (int q = tid; q < DMSA * 2 * DH; q += 256) wl[q] = w_hidden[q];
  if (tid < DMSA) { gl[tid] = gamma[tid]; bl[tid] = beta[tid]; }
  __syncthreads();

  const int p = blockIdx.x * 256 + tid;
  const int n = p >> 9;
  const int s = p & 511;

  const float* mp = msa + ((size_t)s * DN + n) * DMSA;
  float x[64];
  float sum = 0.f, sq = 0.f;
#pragma unroll
  for (int q = 0; q < 16; ++q) {
    float4 v = ((const float4*)mp)[q];
    x[4 * q + 0] = v.x; x[4 * q + 1] = v.y; x[4 * q + 2] = v.z; x[4 * q + 3] = v.w;
    sum += v.x + v.y + v.z + v.w;
    sq  += v.x * v.x + v.y * v.y + v.z * v.z + v.w * v.w;
  }
  const float mu = sum * (1.f / 64.f);
  const float var = sq * (1.f / 64.f) - mu * mu;
  const float rstd = rsqrtf(var + 1e-5f);
#pragma unroll
  for (int d = 0; d < 64; ++d) x[d] = (x[d] - mu) * rstd * gl[d] + bl[d];

  const float sm = smf[s];
  const float sa = sm * invp[0];

  const size_t outbase = ((size_t)n * DH) * DS + s;
  for (int c = 0; c < DH; ++c) {
    float ha = 0.f, hb = 0.f;
#pragma unroll
    for (int d = 0; d < 64; ++d) {
      ha += x[d] * wl[d * 64 + c];
      hb += x[d] * wl[d * 64 + DH + c];
    }
    at[outbase + (size_t)c * DS] = (__bf16)(ha * sa);
    bt[outbase + (size_t)c * DS] = (__bf16)(hb * sm);
  }
}

// ---------------------------------------------------------------------------
// fused: GEMM1 256x256xK512, BK=64 double-buffer (2x64KB), 8 K-steps.
// 128B LDS rows + XOR(row&7) chunk swizzle -> conflict-free ds_read_b128 (T2).
// Loop: STAGE(h+1) early -> 24 ds_reads -> 64 MFMA -> vmcnt(0)+barrier.
// Then op->LDS (swizzled) -> GEMM2 via 32x32x16 (wt [kk][p][16], prefetch).
// ---------------------------------------------------------------------------
__global__ __launch_bounds__(512, 2) void fused_kernel(const __bf16* __restrict__ at,
                                                       const __bf16* __restrict__ bt,
                                                       const __bf16* __restrict__ wt,
                                                       const float* __restrict__ mkf,
                                                       const float* __restrict__ b_out,
                                                       float* __restrict__ out) {
  // dbuf: 2 slots x (A 32KB + B 32KB) = 128KB; aliased: opl 64x2064B = 129KB? No:
  // opl = 64*2064 = 132,096 > 131,072 -> use stride 2064 for 63 rows + last fits:
  // keep 131072 and give opl stride 2048+16 but base compact: 64*2048=128KB + pad
  // region reuse: use stride 2064 up to 63*2064+2048 = 132,080 -> overflow.
  // Solution: opl stride 2064 but only 64 rows needs 132,096; declare 132096.
  __shared__ __align__(128) char smem[132096];

  const int tid = threadIdx.x;
  const int l = tid & 63, w = tid >> 6;
  const int lr = l & 15, lk = l >> 4;
  const int wr = w >> 2, wc = w & 3;

  // XCD-aware swizzle: 48 supertiles of 8x6 blocks.
  const int orig = blockIdx.x;
  const int xcd = orig & 7, sidx = orig >> 3;
  const int stl = sidx / 48, u = sidx % 48;
  const int stg = xcd + stl * 8;
  const int stx = stg % 6, sty = stg / 6;
  const int bx = stx * 8 + (u & 7);
  const int by = sty * 6 + (u >> 3);

  // staging source pointers: 4 chunks each of A/B per thread per step.
  // LDS idx = q*512 + tid -> row = idx>>3 (0..255), chl = idx&7 (16B chunks).
  // LDS[row][chl] holds logical chunk (chl ^ (row&7))  [involution swizzle].
  const __bf16* gA[4];
  const __bf16* gB[4];
#pragma unroll
  for (int q = 0; q < 4; ++q) {
    const int idx = q * 512 + tid;
    const int row = idx >> 3, chl = idx & 7;
    const int src = (chl ^ (row & 7)) * 8;
    gA[q] = at + (size_t)(bx * 256 + row) * 512 + src;
    gB[q] = bt + (size_t)(by * 256 + row) * 512 + src;
  }

  f32x4 acc[8][4];
#pragma unroll
  for (int i = 0; i < 8; ++i)
#pragma unroll
    for (int j = 0; j < 4; ++j) acc[i][j] = (f32x4){0.f, 0.f, 0.f, 0.f};

  auto STAGE = [&](int h, int s) {
    char* da = smem + s * 65536 + tid * 16;
    char* db = da + 32768;
    const int go = h * 64;
#pragma unroll
    for (int q = 0; q < 4; ++q) {
      async16(gA[q] + go, da + q * 8192);
      async16(gB[q] + go, db + q * 8192);
    }
  };

  STAGE(0, 0);
  asm volatile("s_waitcnt vmcnt(0)" ::: "memory");
  __builtin_amdgcn_s_barrier();

#pragma unroll
  for (int h = 0; h < 8; ++h) {
    const char* A = smem + (h & 1) * 65536;
    const char* B = A + 32768;
    if (h < 7) STAGE(h + 1, (h + 1) & 1);

#pragma unroll
    for (int kk = 0; kk < 2; ++kk) {
      bf16x8 af[8], bfr[4];
      const int c = kk * 4 + lk;
      const int phys = (c ^ (lr & 7)) * 16;
#pragma unroll
      for (int fj = 0; fj < 4; ++fj) {
        const int r = wc * 64 + fj * 16 + lr;
        bfr[fj] = *(const bf16x8*)(B + r * 128 + phys);
      }
#pragma unroll
      for (int fi = 0; fi < 8; ++fi) {
        const int r = wr * 128 + fi * 16 + lr;
        af[fi] = *(const bf16x8*)(A + r * 128 + phys);
      }
#pragma unroll
      for (int fi = 0; fi < 8; ++fi)
#pragma unroll
        for (int fj = 0; fj < 4; ++fj)
          acc[fi][fj] = __builtin_amdgcn_mfma_f32_16x16x32_bf16(af[fi], bfr[fj], acc[fi][fj], 0, 0, 0);
    }

    if (h < 7) {
      asm volatile("s_waitcnt vmcnt(0)" ::: "memory");  // next slot fully landed
      __builtin_amdgcn_s_barrier();                      // publish to all waves
    }
  }

  // all waves past their last reads before op-writes clobber the buffers
  asm volatile("" ::: "memory");
  __builtin_amdgcn_s_barrier();
  asm volatile("" ::: "memory");

  // ---- op tile -> LDS bf16 as A2[pair][k'=e*32+d], chunk-XOR swizzled ----
#pragma unroll
  for (int fi = 0; fi < 8; ++fi) {
    const int i_l = wr * 4 + (fi >> 1);
#pragma unroll
    for (int fj = 0; fj < 4; ++fj) {
      const int col = wc * 64 + fj * 16 + lr;
      const int j_l = col >> 5, e = col & 31;
      const int pair = i_l * 8 + j_l;
      const int cw = e * 4 + (fi & 1) * 2 + (lk >> 1);
      const int phys = cw ^ (e & 7);
      bf16x4 pk;
      pk[0] = (__bf16)acc[fi][fj][0];
      pk[1] = (__bf16)acc[fi][fj][1];
      pk[2] = (__bf16)acc[fi][fj][2];
      pk[3] = (__bf16)acc[fi][fj][3];
      *(bf16x4*)(smem + pair * 2064 + phys * 16 + (lk & 1) * 8) = pk;
    }
  }

  // GEMM2 geometry + first B-frag prefetch (hides L2 latency under barrier)
  const int mf = w >> 2, pf = w & 3;
  const int l31 = l & 31, lh = l >> 5;
  const __bf16* wb = wt + (size_t)(pf * 32 + l31) * 16 + lh * 8;  // + kk*2048
  bf16x8 b2 = *(const bf16x8*)(wb);

  asm volatile("s_waitcnt lgkmcnt(0)" ::: "memory");
  __builtin_amdgcn_s_barrier();

  // ---- GEMM2: C2[64 pairs][128 p], K=1024, 32x32x16 MFMA, 1 frag/wave ----
  f32x16 acc2;
#pragma unroll
  for (int q = 0; q < 16; ++q) acc2[q] = 0.f;

  const char* aBase = smem + (mf * 32 + l31) * 2064;
#pragma unroll 4
  for (int kk = 0; kk < 64; ++kk) {
    bf16x8 b2n;
    if (kk < 63) b2n = *(const bf16x8*)(wb + (size_t)(kk + 1) * 2048);
    const int cw = kk * 2 + lh;
    const int phys = cw ^ ((kk >> 1) & 7);
    const bf16x8 a2 = *(const bf16x8*)(aBase + phys * 16);
    acc2 = __builtin_amdgcn_mfma_f32_32x32x16_bf16(a2, b2, acc2, 0, 0, 0);
    b2 = b2n;
  }

  const int p = pf * 32 + l31;
  const float bo = b_out[p];
#pragma unroll
  for (int reg = 0; reg < 16; ++reg) {
    const int pair = mf * 32 + (reg & 3) + 8 * (reg >> 2) + 4 * lh;
    const int i = bx * 8 + (pair >> 3);
    const int j = by * 8 + (pair & 7);
    const float pm = mkf[i] * mkf[j];
    out[((size_t)i * DN + j) * DP + p] = acc2[reg] * pm + bo;
  }
}

extern "C" void kernel_launch(void* const* d_in, const int* in_sizes, int n_in,
                              void* d_out, int out_size, void* d_ws, size_t ws_size,
                              hipStream_t stream) {
  const float* msa      = (const float*)d_in[0];
  const void*  mask     = d_in[1];
  const void*  msa_mask = d_in[2];
  const float* gamma    = (const float*)d_in[3];
  const float* beta     = (const float*)d_in[4];
  const float* w_hidden = (const float*)d_in[5];
  const float* w_out    = (const float*)d_in[6];
  const float* b_out    = (const float*)d_in[7];
  float* out = (float*)d_out;

  char* ws = (char*)d_ws;
  __bf16* at  = (__bf16*)ws;
  __bf16* bt  = (__bf16*)(ws + OFF_BT);
  __bf16* wt  = (__bf16*)(ws + OFF_WT);
  float*  inv = (float*)(ws + OFF_INV);
  float*  smf = (float*)(ws + OFF_SMF);
  float*  mkf = (float*)(ws + OFF_MKF);

  prep_kernel<<<1026, 128, 0, stream>>>(mask, msa_mask, w_out, wt, inv, smf, mkf);
  ln_proj_kernel<<<768, 256, 0, stream>>>(msa, gamma, beta, w_hidden, inv, smf, at, bt);
  fused_kernel<<<2304, 512, 0, stream>>>(at, bt, wt, mkf, b_out, out);
}